// Round 12
// baseline (84.214 us; speedup 1.0000x reference)
//
#include <hip/hip_runtime.h>
#include <hip/hip_bf16.h>

// Ball query: for each (b, p) center, collect first S point indices n with
// ||xyz[b,n] - center[b,p]||^2 < r^2 (index order), zero-fill the rest.
//
// FROZEN FP arithmetic (R6, bit-matches harness "np" ref = XLA w/ contraction):
//   cn = fma(cz,cz, fma(cy,cy, cx*cx))          (contracted mul+reduce)
//   xn = fma(z,z,   fma(y,y,   x*x))
//   dot= fma(cz,z,  fma(cy,y,  cx*x))           (ascending-K FMA)
//   d2 = (cn + xn) - 2*dot ;  valid = d2 < r*r  (all fp32, strict <)
// DO NOT reorder/refactor these ops — a rounding change flips boundary masks.
//
// R12 perf change: dwordx4 point loads (discard 4th dword).
// R6/R7/R11 all plateaued at kernel ~40-44us from three different latency
// structures -> throughput wall. Model: 3 scalar stride-12 wave-loads per
// 64-pt chunk re-touch the same 12 cache lines 3x = 36 L1 line-transactions
// per chunk; 690K chunks / 256 CU x 36 cyc ~= 40us — the measured plateau.
// Fix: one global_load_dwordx4 per lane at byte offset n*12 (4-B aligned,
// legal) covering x,y,z (+1 discarded dword): ~13 line-touches per chunk,
// a ~3x cut in L1 transactions. The single point that would read past the
// buffer end (b=B-1, n=N-1) is covered by a WAVE-UNIFORM scalar fallback
// (only wave 3, last iteration, last batch — off the hot path).
// Block structure unchanged from R11 (4 waves/center, ordered compaction,
// one barrier per 1024 pts). NO global atomics (R9: 7x regression).

typedef float f32x4 __attribute__((ext_vector_type(4)));

__global__ __launch_bounds__(256) void ball_query_block(
    const float* __restrict__ xyz,        // [B, N, 3]
    const float* __restrict__ center,     // [B, P, 3]
    const float* __restrict__ p_radius,   // [1]
    const int*   __restrict__ p_sample,   // [1]
    int* __restrict__ out,                // [B, P, S]
    int B, int N, int P)
{
    const int S = p_sample[0];
    const float r = p_radius[0];
    const float r2 = __fmul_rn(r, r);

    const int c = blockIdx.x;             // one block per center
    const int lane = threadIdx.x & 63;
    const int wv = threadIdx.x >> 6;      // wave 0..3

    const int b = c / P;

    // Center coords + squared norm (same address all lanes -> broadcast)
    const float cx = center[(size_t)c * 3 + 0];
    const float cy = center[(size_t)c * 3 + 1];
    const float cz = center[(size_t)c * 3 + 2];
    // FROZEN: fma-contracted ascending
    const float cn = __builtin_fmaf(cz, cz,
                      __builtin_fmaf(cy, cy, __fmul_rn(cx, cx)));

    const float* xb = xyz + (size_t)b * N * 3;
    int* ob = out + (size_t)c * S;

    __shared__ int counts[2][4];          // double-buffered per-wave totals

    int cnt = 0;
    int buf = 0;
    // N = 16384 = 16 iterations of 1024; early exit at 1024 granularity.
    for (int n0 = 0; n0 < N; n0 += 1024) {
        const int base = n0 + wv * 256 + lane;   // wave wv -> chunks 4wv..4wv+3

        // Phase 1: load 4 chunks. Hot path: 4 back-to-back dwordx4 loads
        // (independent -> clustered). Wave-uniform tail fallback for the one
        // chunk that would read 4B past the end of the xyz buffer.
        float px[4], py[4], pz[4];
        const bool tailwave = (b == B - 1) && (n0 == N - 1024) && (wv == 3);
        if (__builtin_expect(tailwave, 0)) {
#pragma unroll
            for (int j = 0; j < 4; ++j) {
                const int n = base + j * 64;
                px[j] = xb[(size_t)n * 3 + 0];
                py[j] = xb[(size_t)n * 3 + 1];
                pz[j] = xb[(size_t)n * 3 + 2];
            }
        } else {
#pragma unroll
            for (int j = 0; j < 4; ++j) {
                const int n = base + j * 64;
                const f32x4 v = *(const f32x4*)(xb + (size_t)n * 3);
                px[j] = v[0];
                py[j] = v[1];
                pz[j] = v[2];
            }
        }

        // Phase 2: 4 ballot phases, cache masks + per-chunk popcounts
        unsigned long long mm[4];
        int pc[4];
        int wtotal = 0;
#pragma unroll
        for (int j = 0; j < 4; ++j) {
            const float x = px[j], y = py[j], z = pz[j];
            // FROZEN per-point FP sequence:
            const float xn = __builtin_fmaf(z, z,
                              __builtin_fmaf(y, y, __fmul_rn(x, x)));
            const float dot = __builtin_fmaf(cz, z,
                               __builtin_fmaf(cy, y, __fmul_rn(cx, x)));
            const float d2 = __fsub_rn(__fadd_rn(cn, xn), __fmul_rn(2.0f, dot));
            mm[j] = __ballot(d2 < r2);
            pc[j] = __popcll(mm[j]);
            wtotal += pc[j];
        }

        if (lane == 0) counts[buf][wv] = wtotal;
        __syncthreads();

        const int c0 = counts[buf][0];
        const int c1 = counts[buf][1];
        const int c2 = counts[buf][2];
        const int c3 = counts[buf][3];
        int prefix = 0;                   // exclusive prefix over waves < wv
        if (wv > 0) prefix += c0;
        if (wv > 1) prefix += c1;
        if (wv > 2) prefix += c2;
        const int total = (c0 + c1) + (c2 + c3);

        // Phase 3: ordered writes, chunk-by-chunk within the wave
        int off = cnt + prefix;
#pragma unroll
        for (int j = 0; j < 4; ++j) {
            const unsigned long long m = mm[j];
            const bool valid = (m >> lane) & 1ull;
            const int rank = __builtin_amdgcn_mbcnt_hi(
                (unsigned)(m >> 32),
                __builtin_amdgcn_mbcnt_lo((unsigned)m, 0u));
            const int slot = off + rank;
            if (valid && slot < S) {
                ob[slot] = base + j * 64;   // == n for this lane
            }
            off += pc[j];
        }

        cnt += total;
        buf ^= 1;
        if (cnt >= S) break;              // uniform across block
    }

    // Zero-fill unused slots (harness poisons d_out). Valid writes hit
    // [0, cnt), fills hit [cnt, S) — disjoint, no race.
    if (cnt > S) cnt = S;
    for (int s = cnt + (int)threadIdx.x; s < S; s += 256) {
        ob[s] = 0;
    }
}

extern "C" void kernel_launch(void* const* d_in, const int* in_sizes, int n_in,
                              void* d_out, int out_size, void* d_ws, size_t ws_size,
                              hipStream_t stream) {
    const float* xyz      = (const float*)d_in[0];   // [B, N, 3]
    const float* center   = (const float*)d_in[1];   // [B, P, 3]
    const float* p_radius = (const float*)d_in[2];   // scalar
    const int*   p_sample = (const int*)d_in[3];     // scalar

    const int B = 8;
    const int N = in_sizes[0] / (B * 3);   // 16384
    const int P = in_sizes[1] / (B * 3);   // 2048

    int* out = (int*)d_out;

    // One block (4 waves) per center; consecutive blocks share the same
    // xyz[b] slab -> L1/L2 locality for co-resident blocks.
    const int blocks = B * P;              // 16384
    const int threads = 256;

    ball_query_block<<<blocks, threads, 0, stream>>>(
        xyz, center, p_radius, p_sample, out, B, N, P);
}

// Round 13
// 82.508 us; speedup vs baseline: 1.0207x; 1.0207x over previous
//
#include <hip/hip_runtime.h>
#include <hip/hip_bf16.h>

// Ball query: for each (b, p) center, collect first S point indices n with
// ||xyz[b,n] - center[b,p]||^2 < r^2 (index order), zero-fill the rest.
//
// FROZEN FP arithmetic (R6, bit-matches harness "np" ref = XLA w/ contraction):
//   cn = fma(cz,cz, fma(cy,cy, cx*cx))          (contracted mul+reduce)
//   xn = fma(z,z,   fma(y,y,   x*x))            (precomputed in pack kernel)
//   dot= fma(cz,z,  fma(cy,y,  cx*x))           (ascending-K FMA)
//   d2 = (cn + xn) - 2*dot ;  valid = d2 < r*r  (all fp32, strict <)
// DO NOT reorder/refactor these ops — a rounding change flips boundary masks.
// fp32 store/reload of xn is bit-transparent, so precomputing it is safe.
//
// R13: R11 was measured VALU-issue-bound (~27us kernel ~= instr-issue model;
// memory-pattern change R12 was neutral). Cut instructions per pair-eval:
//  (1) pre-kernel packs q[n] = {x, y, z, xn} 16-B aligned into d_ws ->
//      main-loop FROZEN compute 10 -> 7 instrs/chunk, and loads become ONE
//      aligned dwordx4/point (16 line-touches/chunk vs 36, no split, no OOB).
//  (2) skip the write phase when the wave's 4-chunk batch has zero hits
//      (wave-uniform) — most chunks on long scans are empty.
// Block structure unchanged from R11 (4 waves/center, ordered compaction,
// one barrier per 1024 pts). NO global atomics (R9: 7x regression).

typedef float f32x4 __attribute__((ext_vector_type(4)));

__global__ __launch_bounds__(256) void pack_points(
    const float* __restrict__ xyz,   // [B*N, 3]
    f32x4* __restrict__ q,           // [B*N] packed {x,y,z,xn}
    int total)
{
    const int n = blockIdx.x * blockDim.x + threadIdx.x;
    if (n >= total) return;
    const float x = xyz[(size_t)n * 3 + 0];
    const float y = xyz[(size_t)n * 3 + 1];
    const float z = xyz[(size_t)n * 3 + 2];
    // FROZEN xn sequence:
    const float xn = __builtin_fmaf(z, z,
                      __builtin_fmaf(y, y, __fmul_rn(x, x)));
    f32x4 v;
    v[0] = x; v[1] = y; v[2] = z; v[3] = xn;
    q[n] = v;
}

__global__ __launch_bounds__(256) void ball_query_block(
    const f32x4* __restrict__ q,          // [B*N] packed {x,y,z,xn}
    const float* __restrict__ center,     // [B, P, 3]
    const float* __restrict__ p_radius,   // [1]
    const int*   __restrict__ p_sample,   // [1]
    int* __restrict__ out,                // [B, P, S]
    int B, int N, int P)
{
    const int S = p_sample[0];
    const float r = p_radius[0];
    const float r2 = __fmul_rn(r, r);

    const int c = blockIdx.x;             // one block per center
    const int lane = threadIdx.x & 63;
    const int wv = threadIdx.x >> 6;      // wave 0..3

    const int b = c / P;

    // Center coords + squared norm (same address all lanes -> broadcast)
    const float cx = center[(size_t)c * 3 + 0];
    const float cy = center[(size_t)c * 3 + 1];
    const float cz = center[(size_t)c * 3 + 2];
    // FROZEN: fma-contracted ascending
    const float cn = __builtin_fmaf(cz, cz,
                      __builtin_fmaf(cy, cy, __fmul_rn(cx, cx)));

    const f32x4* qb = q + (size_t)b * N;
    int* ob = out + (size_t)c * S;

    __shared__ int counts[2][4];          // double-buffered per-wave totals

    int cnt = 0;
    int buf = 0;
    // N = 16384 = 16 iterations of 1024; early exit at 1024 granularity.
    for (int n0 = 0; n0 < N; n0 += 1024) {
        const int base = n0 + wv * 256 + lane;   // wave wv -> chunks 4wv..4wv+3

        // Phase 1: 4 aligned dwordx4 loads (independent -> clustered)
        f32x4 v[4];
#pragma unroll
        for (int j = 0; j < 4; ++j) {
            v[j] = qb[base + j * 64];
        }

        // Phase 2: 4 ballot phases, cache masks + per-chunk popcounts
        unsigned long long mm[4];
        int pc[4];
        int wtotal = 0;
#pragma unroll
        for (int j = 0; j < 4; ++j) {
            const float x = v[j][0], y = v[j][1], z = v[j][2];
            const float xn = v[j][3];     // FROZEN xn (precomputed, bit-exact)
            // FROZEN per-pair FP sequence:
            const float dot = __builtin_fmaf(cz, z,
                               __builtin_fmaf(cy, y, __fmul_rn(cx, x)));
            const float d2 = __fsub_rn(__fadd_rn(cn, xn), __fmul_rn(2.0f, dot));
            mm[j] = __ballot(d2 < r2);
            pc[j] = __popcll(mm[j]);
            wtotal += pc[j];
        }

        if (lane == 0) counts[buf][wv] = wtotal;
        __syncthreads();

        const int c0 = counts[buf][0];
        const int c1 = counts[buf][1];
        const int c2 = counts[buf][2];
        const int c3 = counts[buf][3];
        int prefix = 0;                   // exclusive prefix over waves < wv
        if (wv > 0) prefix += c0;
        if (wv > 1) prefix += c1;
        if (wv > 2) prefix += c2;
        const int total = (c0 + c1) + (c2 + c3);

        // Phase 3: ordered writes — skipped entirely when this wave found
        // nothing (wave-uniform; the common case on long sparse scans).
        if (wtotal != 0) {
            int off = cnt + prefix;
#pragma unroll
            for (int j = 0; j < 4; ++j) {
                const unsigned long long m = mm[j];
                const bool valid = (m >> lane) & 1ull;
                const int rank = __builtin_amdgcn_mbcnt_hi(
                    (unsigned)(m >> 32),
                    __builtin_amdgcn_mbcnt_lo((unsigned)m, 0u));
                const int slot = off + rank;
                if (valid && slot < S) {
                    ob[slot] = base + j * 64;   // == n for this lane
                }
                off += pc[j];
            }
        }

        cnt += total;
        buf ^= 1;
        if (cnt >= S) break;              // uniform across block
    }

    // Zero-fill unused slots (harness poisons d_out). Valid writes hit
    // [0, cnt), fills hit [cnt, S) — disjoint, no race.
    if (cnt > S) cnt = S;
    for (int s = cnt + (int)threadIdx.x; s < S; s += 256) {
        ob[s] = 0;
    }
}

extern "C" void kernel_launch(void* const* d_in, const int* in_sizes, int n_in,
                              void* d_out, int out_size, void* d_ws, size_t ws_size,
                              hipStream_t stream) {
    const float* xyz      = (const float*)d_in[0];   // [B, N, 3]
    const float* center   = (const float*)d_in[1];   // [B, P, 3]
    const float* p_radius = (const float*)d_in[2];   // scalar
    const int*   p_sample = (const int*)d_in[3];     // scalar

    const int B = 8;
    const int N = in_sizes[0] / (B * 3);   // 16384
    const int P = in_sizes[1] / (B * 3);   // 2048

    int* out = (int*)d_out;
    f32x4* q = (f32x4*)d_ws;               // B*N*16 B = 2 MB << ws_size

    // Pass 1: pack {x,y,z,xn} (runs every launch; ws is re-poisoned each call)
    const int total = B * N;               // 131072
    pack_points<<<(total + 255) / 256, 256, 0, stream>>>(xyz, q, total);

    // Pass 2: one block (4 waves) per center.
    const int blocks = B * P;              // 16384
    const int threads = 256;
    ball_query_block<<<blocks, threads, 0, stream>>>(
        q, center, p_radius, p_sample, out, B, N, P);
}